// Round 5
// baseline (414.212 us; speedup 1.0000x reference)
//
#include <hip/hip_runtime.h>

#define DFEAT 64
#define EPSBN 1e-5f
#define SCB 2048      // elements per scan block (256 threads x 8)

// ---------------- rank pass: in-row rank + degrees via L2 atomics ----------------
// Round-3 post-mortem: the chunked LDS histogram (hist2d) existed only to make
// a DETERMINISTIC in-row rank; but summation order within a dst row is
// irrelevant (fp-tolerance), so a returning atomicAdd gives a valid unique
// rank directly. This kills hist2d's 13x edge-list re-read (166MB) and the
// colscan 10MB round trip. cnt_in/cnt_out are 400KB each -> L2-resident;
// 3.2M random-address atomics, ~16 hits/address over the whole pass -> no
// serialization hotspot.
__global__ __launch_bounds__(256) void rank_kernel(
        const int* __restrict__ src, const int* __restrict__ dst,
        int* __restrict__ cnt_in, int* __restrict__ cnt_out,
        unsigned short* __restrict__ rank, int E) {
    int i = blockIdx.x * 256 + threadIdx.x;   // int4 group index
    int nvec = E >> 2;
    if (i < nvec) {
        int4 s4 = ((const int4*)src)[i];
        int4 d4 = ((const int4*)dst)[i];
        ushort4 r;
        r.x = (unsigned short)atomicAdd(&cnt_in[d4.x], 1);
        r.y = (unsigned short)atomicAdd(&cnt_in[d4.y], 1);
        r.z = (unsigned short)atomicAdd(&cnt_in[d4.z], 1);
        r.w = (unsigned short)atomicAdd(&cnt_in[d4.w], 1);
        atomicAdd(&cnt_out[s4.x], 1);
        atomicAdd(&cnt_out[s4.y], 1);
        atomicAdd(&cnt_out[s4.z], 1);
        atomicAdd(&cnt_out[s4.w], 1);
        ((ushort4*)rank)[i] = r;
    }
    int e = (nvec << 2) + i;                  // <=3 tail edges, threads 0..2
    if (e < E && i < 4) {
        rank[e] = (unsigned short)atomicAdd(&cnt_in[dst[e]], 1);
        atomicAdd(&cnt_out[src[e]], 1);
    }
}

// ---------------- scan pass 1: per-block sums of deg_in (== cnt_in) ----------------
__global__ void scan1_kernel(const int* __restrict__ deg, int* __restrict__ bsum, int N) {
    __shared__ int red[256];
    int t = threadIdx.x;
    int base = blockIdx.x * SCB + t * 8;
    int s = 0;
    #pragma unroll
    for (int j = 0; j < 8; ++j) { int idx = base + j; if (idx < N) s += deg[idx]; }
    red[t] = s;
    __syncthreads();
    for (int d = 128; d > 0; d >>= 1) { if (t < d) red[t] += red[t + d]; __syncthreads(); }
    if (t == 0) bsum[blockIdx.x] = red[0];
}

// ---------------- scan pass 2: one-wave shuffle exclusive scan (NB <= 64) ----------------
__global__ void scan2_kernel(int* __restrict__ bsum, int* __restrict__ row_start, int NB, int N) {
    int lane = threadIdx.x & 63;
    int v = (lane < NB) ? bsum[lane] : 0;
    int incl = v;
    #pragma unroll
    for (int off = 1; off < 64; off <<= 1) {
        int t = __shfl_up(incl, off);
        if (lane >= off) incl += t;
    }
    if (lane < NB) bsum[lane] = incl - v;
    if (lane == 63) row_start[N] = incl;   // total == E
}

// ---------------- scan pass 3: full exclusive scan -> row_start ----------------
__global__ void scan3_kernel(const int* __restrict__ deg, const int* __restrict__ bsum,
                             int* __restrict__ row_start, int N) {
    __shared__ int sc[256];
    int t = threadIdx.x;
    int base = blockIdx.x * SCB + t * 8;
    int v[8], ex[8];
    int s = 0;
    #pragma unroll
    for (int j = 0; j < 8; ++j) {
        int idx = base + j;
        v[j] = (idx < N) ? deg[idx] : 0;
        ex[j] = s;
        s += v[j];
    }
    sc[t] = s;
    __syncthreads();
    for (int d = 1; d < 256; d <<= 1) {
        int vv = (t >= d) ? sc[t - d] : 0;
        __syncthreads();
        sc[t] += vv;
        __syncthreads();
    }
    int toff = sc[t] - s + bsum[blockIdx.x];
    #pragma unroll
    for (int j = 0; j < 8; ++j) {
        int idx = base + j;
        if (idx < N) row_start[idx] = toff + ex[j];
    }
}

// ---------------- place edges: slot = row_start[dst] + rank[e] ----------------
__global__ __launch_bounds__(256) void fill_kernel(
        const int* __restrict__ src, const int* __restrict__ dst,
        const unsigned short* __restrict__ rank,
        const int* __restrict__ cnt_out, const int* __restrict__ row_start,
        int2* __restrict__ epack, int E) {
    int i = blockIdx.x * 256 + threadIdx.x;   // int4 group index
    int nvec = E >> 2;
    if (i < nvec) {
        int4 s4 = ((const int4*)src)[i];
        int4 d4 = ((const int4*)dst)[i];
        ushort4 r4 = ((const ushort4*)rank)[i];
        int slot; float coef;
        slot = row_start[d4.x] + (int)r4.x;
        coef = rsqrtf((float)max(cnt_out[s4.x], 1));
        epack[slot] = make_int2(s4.x, __float_as_int(coef));
        slot = row_start[d4.y] + (int)r4.y;
        coef = rsqrtf((float)max(cnt_out[s4.y], 1));
        epack[slot] = make_int2(s4.y, __float_as_int(coef));
        slot = row_start[d4.z] + (int)r4.z;
        coef = rsqrtf((float)max(cnt_out[s4.z], 1));
        epack[slot] = make_int2(s4.z, __float_as_int(coef));
        slot = row_start[d4.w] + (int)r4.w;
        coef = rsqrtf((float)max(cnt_out[s4.w], 1));
        epack[slot] = make_int2(s4.w, __float_as_int(coef));
    }
    int e = (nvec << 2) + i;                  // <=3 tail edges
    if (e < E && i < 4) {
        int slot = row_start[dst[e]] + (int)rank[e];
        float coef = rsqrtf((float)max(cnt_out[src[e]], 1));
        epack[slot] = make_int2(src[e], __float_as_int(coef));
    }
}

// ---------------- fused SpMM + GEMM + BN partials: 4 rows per wave ----------------
// Each wave holds 4 full agg rows across its 64 lanes (acc[q] = column lane).
// GEMM tail: y[r][c] = sum_k agg[r][k]*W[k][c] in-wave via v_readlane
// (SGPR broadcast) x Wl[k][lane] from LDS (1 ds_read feeds 4 rows' FMAs).
// BN column partials accumulated in registers (lane == column), one LDS tree
// + 128-float partial store per block.
__global__ __launch_bounds__(256, 8) void spmm_gemm_kernel(
        const float* __restrict__ x, const int* __restrict__ row_start,
        const int2* __restrict__ epack, const float* __restrict__ W,
        const float* __restrict__ bvec, float* __restrict__ y,
        float* __restrict__ partial, int N) {
    __shared__ float Wl[DFEAT * DFEAT];
    __shared__ float red_s[4][DFEAT];
    __shared__ float red_q[4][DFEAT];
    int tid = threadIdx.x;
    {
        const float4* W4 = (const float4*)W;
        float4* Wl4 = (float4*)Wl;
        #pragma unroll
        for (int j = 0; j < 4; ++j) Wl4[tid + 256 * j] = W4[tid + 256 * j];
    }
    __syncthreads();

    int lane = tid & 63;
    int w = tid >> 6;
    int r0 = blockIdx.x * 16 + w * 4;
    float bv = bvec[lane];

    float acc[4];
    #pragma unroll
    for (int q = 0; q < 4; ++q) {
        float a = 0.f;
        int r = r0 + q;
        if (r < N) {
            int beg = row_start[r];
            int end = row_start[r + 1];
            for (int cb = beg; cb < end; cb += 64) {
                int take = min(64, end - cb);
                int2 p = (lane < take) ? epack[cb + lane] : make_int2(0, 0);
                int j = 0;
                for (; j + 8 <= take; j += 8) {
                    int sj[8]; float cj[8], v[8];
                    #pragma unroll
                    for (int u = 0; u < 8; ++u) {
                        sj[u] = __builtin_amdgcn_readlane(p.x, j + u);
                        cj[u] = __int_as_float(__builtin_amdgcn_readlane(p.y, j + u));
                    }
                    #pragma unroll
                    for (int u = 0; u < 8; ++u) v[u] = x[(size_t)sj[u] * DFEAT + lane];
                    #pragma unroll
                    for (int u = 0; u < 8; ++u) a = fmaf(v[u], cj[u], a);
                }
                for (; j < take; ++j) {
                    int s = __builtin_amdgcn_readlane(p.x, j);
                    float c = __int_as_float(__builtin_amdgcn_readlane(p.y, j));
                    a = fmaf(x[(size_t)s * DFEAT + lane], c, a);
                }
            }
            a *= rsqrtf((float)max(end - beg, 1));   // norm_dst: a = agg[r][lane]
        }
        acc[q] = a;
    }

    // ---- in-wave GEMM tail, W read shared by 4 rows
    float yo0 = 0.f, yo1 = 0.f, yo2 = 0.f, yo3 = 0.f;
    int ai0 = __float_as_int(acc[0]);
    int ai1 = __float_as_int(acc[1]);
    int ai2 = __float_as_int(acc[2]);
    int ai3 = __float_as_int(acc[3]);
    #pragma unroll 8
    for (int k = 0; k < DFEAT; ++k) {
        float wk = Wl[k * DFEAT + lane];     // conflict-free, 1 read / 4 rows
        yo0 = fmaf(__int_as_float(__builtin_amdgcn_readlane(ai0, k)), wk, yo0);
        yo1 = fmaf(__int_as_float(__builtin_amdgcn_readlane(ai1, k)), wk, yo1);
        yo2 = fmaf(__int_as_float(__builtin_amdgcn_readlane(ai2, k)), wk, yo2);
        yo3 = fmaf(__int_as_float(__builtin_amdgcn_readlane(ai3, k)), wk, yo3);
    }

    float yq[4] = {yo0, yo1, yo2, yo3};
    float ps = 0.f, pq = 0.f;                // column (=lane) partial stats
    #pragma unroll
    for (int q = 0; q < 4; ++q) {
        int r = r0 + q;
        if (r < N) {
            float yv = bv + yq[q];
            y[(size_t)r * DFEAT + lane] = yv;
            ps += yv;
            pq = fmaf(yv, yv, pq);
        }
    }

    red_s[w][lane] = ps;
    red_q[w][lane] = pq;
    __syncthreads();
    if (w == 0) {
        float s = red_s[0][lane] + red_s[1][lane] + red_s[2][lane] + red_s[3][lane];
        float q2 = red_q[0][lane] + red_q[1][lane] + red_q[2][lane] + red_q[3][lane];
        float* p = partial + (size_t)blockIdx.x * 128;
        p[lane] = s;
        p[64 + lane] = q2;
    }
}

// ---------------- BN stats finalize: G partials -> sums/sumsq (adjacent) ----------------
// 16 blocks x 32 stripes; 16 atomics per address (trivial serialization).
__global__ void bnstat2_kernel(const float* __restrict__ partial,
                               float* __restrict__ sums, int G) {
    int t = threadIdx.x;
    int j = t & 127, h = t >> 7;
    int stripe = blockIdx.x * 2 + h;         // 0..31
    float s = 0.f;
    for (int g = stripe; g < G; g += 32)
        s += partial[(size_t)g * 128 + j];
    __shared__ float red[2][128];
    red[h][j] = s;
    __syncthreads();
    if (h == 0) atomicAdd(&sums[j], red[0][j] + red[1][j]);   // sums||sumsq contiguous
}

// ---------------- BN (batch stats) + ReLU + residual, float4, in place on y ----------------
__global__ void bn_relu_res_kernel(const float* __restrict__ x,
                                   const float* __restrict__ sums,
                                   const float* __restrict__ sumsq,
                                   const float* __restrict__ gamma,
                                   const float* __restrict__ beta,
                                   float* __restrict__ y, int n4, float inv_n) {
    int i = blockIdx.x * blockDim.x + threadIdx.x;   // float4 index
    if (i < n4) {
        int c0 = (i << 2) & (DFEAT - 1);
        float4 yv = ((const float4*)y)[i];
        float4 xv = ((const float4*)x)[i];
        float o[4] = {yv.x, yv.y, yv.z, yv.w};
        float xi[4] = {xv.x, xv.y, xv.z, xv.w};
        #pragma unroll
        for (int k = 0; k < 4; ++k) {
            int c = c0 + k;
            float mean = sums[c] * inv_n;
            float var = sumsq[c] * inv_n - mean * mean;
            float inv = rsqrtf(var + EPSBN);
            float v = (o[k] - mean) * inv * gamma[c] + beta[c];
            o[k] = xi[k] + fmaxf(v, 0.f);
        }
        ((float4*)y)[i] = make_float4(o[0], o[1], o[2], o[3]);
    }
}

extern "C" void kernel_launch(void* const* d_in, const int* in_sizes, int n_in,
                              void* d_out, int out_size, void* d_ws, size_t ws_size,
                              hipStream_t stream) {
    const float* x     = (const float*)d_in[0];
    const int*   src   = (const int*)d_in[1];
    const int*   dst   = (const int*)d_in[2];
    const float* W     = (const float*)d_in[3];
    const float* bvec  = (const float*)d_in[4];
    const float* gamma = (const float*)d_in[5];
    const float* beta  = (const float*)d_in[6];
    float* out = (float*)d_out;   // y, written once by fused spmm+gemm

    const int n_nodes = in_sizes[0] / DFEAT;
    const int E = in_sizes[1];
    const int NB = (n_nodes + SCB - 1) / SCB;

    // ws layout:
    //   epack    E int2          (12.8MB)
    //   rank     E u16 (+pad)    ( 3.2MB)
    //   cnt_in   N int   --+
    //   cnt_out  N int     |  one contiguous memset region
    //   sums     64 f      |
    //   sumsq    64 f    --+
    //   row_start N+1 int
    //   bsum     64 int
    //   partial  grid_sg*128 f   ( 3.2MB)
    char* wsb = (char*)d_ws;
    int2* epack           = (int2*)wsb;
    unsigned short* rank  = (unsigned short*)(wsb + (size_t)E * 8);
    size_t rank_bytes     = (((size_t)E * 2) + 15) & ~(size_t)15;
    int*  cnt_in     = (int*)((char*)rank + rank_bytes);
    int*  cnt_out    = cnt_in + n_nodes;
    float* sums      = (float*)(cnt_out + n_nodes);
    float* sumsq     = sums + DFEAT;
    int*  row_start  = (int*)(sumsq + DFEAT);
    int*  bsum       = row_start + n_nodes + 1;
    float* partial   = (float*)(bsum + 64);

    // zero: cnt_in + cnt_out + sums + sumsq (contiguous)
    hipMemsetAsync(cnt_in, 0, (2 * (size_t)n_nodes + 2 * DFEAT) * sizeof(int), stream);

    int nvec = E >> 2;
    int egrid = (nvec + 255) / 256;
    rank_kernel<<<egrid, 256, 0, stream>>>(src, dst, cnt_in, cnt_out, rank, E);

    scan1_kernel<<<NB, 256, 0, stream>>>(cnt_in, bsum, n_nodes);
    scan2_kernel<<<1, 64, 0, stream>>>(bsum, row_start, NB, n_nodes);
    scan3_kernel<<<NB, 256, 0, stream>>>(cnt_in, bsum, row_start, n_nodes);

    fill_kernel<<<egrid, 256, 0, stream>>>(src, dst, rank, cnt_out, row_start,
                                           epack, E);

    int grid_sg = (n_nodes + 15) / 16;
    spmm_gemm_kernel<<<grid_sg, 256, 0, stream>>>(x, row_start, epack,
                                                  W, bvec, out, partial, n_nodes);

    bnstat2_kernel<<<16, 256, 0, stream>>>(partial, sums, grid_sg);

    int n4 = n_nodes * DFEAT / 4;
    bn_relu_res_kernel<<<(n4 + 255) / 256, 256, 0, stream>>>(
        x, sums, sumsq, gamma, beta, out, n4, 1.0f / (float)n_nodes);
}

// Round 6
// 329.591 us; speedup vs baseline: 1.2567x; 1.2567x over previous
//
#include <hip/hip_runtime.h>

#define DFEAT 64
#define EPSBN 1e-5f
#define SCB 2048      // elements per scan block (256 threads x 8)
#define CHUNK_LG 15
#define CHUNK (1 << CHUNK_LG)   // 32768 edges per chunk
#define RNG 16384     // nodes per partition: 64KB packed LDS hist, P=7 (was 13)

// ---------------- LDS-privatized PACKED dual histogram + chunk-local rank ----------------
// one 64KB LDS array: low16 = dst count, high16 = src count. int4 edge loads +
// manual prefetch. Round-5 post-mortem: random global atomics cost one 32B
// memory-side writeback EACH (103MB for 3.2M atomics, 155us) -- LDS atomics +
// contiguous range flushes are the only cheap path, so the chunked histogram
// stays. RNG doubled 8192->16384: P drops 13->7, halving the guarded re-scan
// work (P*E edge visits); 64KB LDS still allows 2 blocks/CU.
__global__ __launch_bounds__(256) void hist2d_kernel(
        const int* __restrict__ src, const int* __restrict__ dst,
        unsigned short* __restrict__ lrank, unsigned short* __restrict__ cnt,
        int* __restrict__ deg_out, int E, int N, int N_pad) {
    __shared__ int h[RNG];
    int tid = threadIdx.x;
    int c = blockIdx.x, p = blockIdx.y;
    int nbeg = p * RNG;
    for (int i = tid; i < RNG; i += 256) h[i] = 0;
    __syncthreads();

    int ebeg = c << CHUNK_LG;
    int eend = min(ebeg + CHUNK, E);
    int nvec = (eend - ebeg) >> 2;              // full int4 groups
    const int4* src4 = (const int4*)(src + ebeg);
    const int4* dst4 = (const int4*)(dst + ebeg);

    int i = tid;
    int4 s4 = make_int4(0, 0, 0, 0), d4 = s4;
    if (i < nvec) { s4 = src4[i]; d4 = dst4[i]; }
    while (i < nvec) {
        int inext = i + 256;
        int4 sn = make_int4(0, 0, 0, 0), dn = sn;
        if (inext < nvec) { sn = src4[inext]; dn = dst4[inext]; }   // prefetch
        int e = ebeg + (i << 2);
        {
            unsigned int so, dof;
            so = (unsigned int)(s4.x - nbeg); if (so < RNG) atomicAdd(&h[so], 0x10000);
            so = (unsigned int)(s4.y - nbeg); if (so < RNG) atomicAdd(&h[so], 0x10000);
            so = (unsigned int)(s4.z - nbeg); if (so < RNG) atomicAdd(&h[so], 0x10000);
            so = (unsigned int)(s4.w - nbeg); if (so < RNG) atomicAdd(&h[so], 0x10000);
            dof = (unsigned int)(d4.x - nbeg);
            if (dof < RNG) lrank[e + 0] = (unsigned short)(atomicAdd(&h[dof], 1) & 0xffff);
            dof = (unsigned int)(d4.y - nbeg);
            if (dof < RNG) lrank[e + 1] = (unsigned short)(atomicAdd(&h[dof], 1) & 0xffff);
            dof = (unsigned int)(d4.z - nbeg);
            if (dof < RNG) lrank[e + 2] = (unsigned short)(atomicAdd(&h[dof], 1) & 0xffff);
            dof = (unsigned int)(d4.w - nbeg);
            if (dof < RNG) lrank[e + 3] = (unsigned short)(atomicAdd(&h[dof], 1) & 0xffff);
        }
        s4 = sn; d4 = dn; i = inext;
    }
    for (int e = ebeg + (nvec << 2) + tid; e < eend; e += 256) {
        unsigned int so = (unsigned int)(src[e] - nbeg);
        unsigned int dof = (unsigned int)(dst[e] - nbeg);
        if (so < RNG) atomicAdd(&h[so], 0x10000);
        if (dof < RNG) lrank[e] = (unsigned short)(atomicAdd(&h[dof], 1) & 0xffff);
    }
    __syncthreads();

    for (int i2 = tid; i2 < RNG; i2 += 256) {
        int n = nbeg + i2;
        if (n < N) {
            unsigned int v = (unsigned int)h[i2];
            unsigned int vo = v >> 16;
            if (vo) atomicAdd(&deg_out[n], (int)vo);   // contiguous lanes -> batched
            cnt[(size_t)c * N_pad + n] = (unsigned short)(v & 0xffffu);
        }
    }
}

// ---------------- column scan: per-node exclusive prefix over chunks ----------------
__global__ void colscan_kernel(unsigned short* __restrict__ cnt,
                               int* __restrict__ deg_in, int N, int N_pad, int C) {
    int n = blockIdx.x * blockDim.x + threadIdx.x;
    if (n >= N) return;
    int run = 0;
    for (int c = 0; c < C; ++c) {
        size_t idx = (size_t)c * N_pad + n;
        int v = cnt[idx];
        cnt[idx] = (unsigned short)run;
        run += v;
    }
    deg_in[n] = run;
}

// ---------------- scan pass 1: per-block sums of deg_in ----------------
__global__ void scan1_kernel(const int* __restrict__ deg, int* __restrict__ bsum, int N) {
    __shared__ int red[256];
    int t = threadIdx.x;
    int base = blockIdx.x * SCB + t * 8;
    int s = 0;
    #pragma unroll
    for (int j = 0; j < 8; ++j) { int idx = base + j; if (idx < N) s += deg[idx]; }
    red[t] = s;
    __syncthreads();
    for (int d = 128; d > 0; d >>= 1) { if (t < d) red[t] += red[t + d]; __syncthreads(); }
    if (t == 0) bsum[blockIdx.x] = red[0];
}

// ---------------- scan pass 2: one-wave shuffle exclusive scan (NB <= 64) ----------------
__global__ void scan2_kernel(int* __restrict__ bsum, int* __restrict__ row_start, int NB, int N) {
    int lane = threadIdx.x & 63;
    int v = (lane < NB) ? bsum[lane] : 0;
    int incl = v;
    #pragma unroll
    for (int off = 1; off < 64; off <<= 1) {
        int t = __shfl_up(incl, off);
        if (lane >= off) incl += t;
    }
    if (lane < NB) bsum[lane] = incl - v;
    if (lane == 63) row_start[N] = incl;   // total == E
}

// ---------------- scan pass 3: full exclusive scan -> row_start ----------------
__global__ void scan3_kernel(const int* __restrict__ deg, const int* __restrict__ bsum,
                             int* __restrict__ row_start, int N) {
    __shared__ int sc[256];
    int t = threadIdx.x;
    int base = blockIdx.x * SCB + t * 8;
    int v[8], ex[8];
    int s = 0;
    #pragma unroll
    for (int j = 0; j < 8; ++j) {
        int idx = base + j;
        v[j] = (idx < N) ? deg[idx] : 0;
        ex[j] = s;
        s += v[j];
    }
    sc[t] = s;
    __syncthreads();
    for (int d = 1; d < 256; d <<= 1) {
        int vv = (t >= d) ? sc[t - d] : 0;
        __syncthreads();
        sc[t] += vv;
        __syncthreads();
    }
    int toff = sc[t] - s + bsum[blockIdx.x];
    #pragma unroll
    for (int j = 0; j < 8; ++j) {
        int idx = base + j;
        if (idx < N) row_start[idx] = toff + ex[j];
    }
}

// ---------------- place edges: slot = row_start[d] + pref[c][d] + lrank[e] ----------------
__global__ void fill_kernel(const int* __restrict__ src, const int* __restrict__ dst,
                            const unsigned short* __restrict__ lrank,
                            const unsigned short* __restrict__ cnt,
                            const int* __restrict__ deg_out, const int* __restrict__ row_start,
                            int2* __restrict__ epack, int E, int N_pad) {
    int e = blockIdx.x * blockDim.x + threadIdx.x;
    if (e < E) {
        int d = dst[e], s = src[e];
        int c = e >> CHUNK_LG;
        float coef = rsqrtf((float)max(deg_out[s], 1));
        int slot = row_start[d] + (int)cnt[(size_t)c * N_pad + d] + (int)lrank[e];
        epack[slot] = make_int2(s, __float_as_int(coef));
    }
}

// ---------------- fused SpMM + GEMM + BN partials: 4 rows per wave ----------------
// Each wave holds 4 full agg rows across its 64 lanes (acc[q] = column lane).
// GEMM tail: y[r][c] = sum_k agg[r][k]*W[k][c] in-wave via v_readlane
// (SGPR broadcast) x Wl[k][lane] from LDS (1 ds_read feeds 4 rows' FMAs).
// BN column partials accumulated in registers (lane == column), one LDS tree
// + 128-float partial store per block (replaces the bnstat1 25.6MB re-read).
__global__ __launch_bounds__(256, 8) void spmm_gemm_kernel(
        const float* __restrict__ x, const int* __restrict__ row_start,
        const int2* __restrict__ epack, const float* __restrict__ W,
        const float* __restrict__ bvec, float* __restrict__ y,
        float* __restrict__ partial, int N) {
    __shared__ float Wl[DFEAT * DFEAT];
    __shared__ float red_s[4][DFEAT];
    __shared__ float red_q[4][DFEAT];
    int tid = threadIdx.x;
    {
        const float4* W4 = (const float4*)W;
        float4* Wl4 = (float4*)Wl;
        #pragma unroll
        for (int j = 0; j < 4; ++j) Wl4[tid + 256 * j] = W4[tid + 256 * j];
    }
    __syncthreads();

    int lane = tid & 63;
    int w = tid >> 6;
    int r0 = blockIdx.x * 16 + w * 4;
    float bv = bvec[lane];

    float acc[4];
    #pragma unroll
    for (int q = 0; q < 4; ++q) {
        float a = 0.f;
        int r = r0 + q;
        if (r < N) {
            int beg = row_start[r];
            int end = row_start[r + 1];
            for (int cb = beg; cb < end; cb += 64) {
                int take = min(64, end - cb);
                int2 p = (lane < take) ? epack[cb + lane] : make_int2(0, 0);
                int j = 0;
                for (; j + 8 <= take; j += 8) {
                    int sj[8]; float cj[8], v[8];
                    #pragma unroll
                    for (int u = 0; u < 8; ++u) {
                        sj[u] = __builtin_amdgcn_readlane(p.x, j + u);
                        cj[u] = __int_as_float(__builtin_amdgcn_readlane(p.y, j + u));
                    }
                    #pragma unroll
                    for (int u = 0; u < 8; ++u) v[u] = x[(size_t)sj[u] * DFEAT + lane];
                    #pragma unroll
                    for (int u = 0; u < 8; ++u) a = fmaf(v[u], cj[u], a);
                }
                for (; j < take; ++j) {
                    int s = __builtin_amdgcn_readlane(p.x, j);
                    float c = __int_as_float(__builtin_amdgcn_readlane(p.y, j));
                    a = fmaf(x[(size_t)s * DFEAT + lane], c, a);
                }
            }
            a *= rsqrtf((float)max(end - beg, 1));   // norm_dst: a = agg[r][lane]
        }
        acc[q] = a;
    }

    // ---- in-wave GEMM tail, W read shared by 4 rows
    float yo0 = 0.f, yo1 = 0.f, yo2 = 0.f, yo3 = 0.f;
    int ai0 = __float_as_int(acc[0]);
    int ai1 = __float_as_int(acc[1]);
    int ai2 = __float_as_int(acc[2]);
    int ai3 = __float_as_int(acc[3]);
    #pragma unroll 8
    for (int k = 0; k < DFEAT; ++k) {
        float wk = Wl[k * DFEAT + lane];     // conflict-free, 1 read / 4 rows
        yo0 = fmaf(__int_as_float(__builtin_amdgcn_readlane(ai0, k)), wk, yo0);
        yo1 = fmaf(__int_as_float(__builtin_amdgcn_readlane(ai1, k)), wk, yo1);
        yo2 = fmaf(__int_as_float(__builtin_amdgcn_readlane(ai2, k)), wk, yo2);
        yo3 = fmaf(__int_as_float(__builtin_amdgcn_readlane(ai3, k)), wk, yo3);
    }

    float yq[4] = {yo0, yo1, yo2, yo3};
    float ps = 0.f, pq = 0.f;                // column (=lane) partial stats
    #pragma unroll
    for (int q = 0; q < 4; ++q) {
        int r = r0 + q;
        if (r < N) {
            float yv = bv + yq[q];
            y[(size_t)r * DFEAT + lane] = yv;
            ps += yv;
            pq = fmaf(yv, yv, pq);
        }
    }

    red_s[w][lane] = ps;
    red_q[w][lane] = pq;
    __syncthreads();
    if (w == 0) {
        float s = red_s[0][lane] + red_s[1][lane] + red_s[2][lane] + red_s[3][lane];
        float q2 = red_q[0][lane] + red_q[1][lane] + red_q[2][lane] + red_q[3][lane];
        float* p = partial + (size_t)blockIdx.x * 128;
        p[lane] = s;
        p[64 + lane] = q2;
    }
}

// ---------------- BN stats finalize: G partials -> sums/sumsq (adjacent) ----------------
// 16 blocks x 32 stripes; 16 atomics per address (trivial serialization).
__global__ void bnstat2_kernel(const float* __restrict__ partial,
                               float* __restrict__ sums, int G) {
    int t = threadIdx.x;
    int j = t & 127, h = t >> 7;
    int stripe = blockIdx.x * 2 + h;         // 0..31
    float s = 0.f;
    for (int g = stripe; g < G; g += 32)
        s += partial[(size_t)g * 128 + j];
    __shared__ float red[2][128];
    red[h][j] = s;
    __syncthreads();
    if (h == 0) atomicAdd(&sums[j], red[0][j] + red[1][j]);   // sums||sumsq contiguous
}

// ---------------- BN (batch stats) + ReLU + residual, float4, in place on y ----------------
__global__ void bn_relu_res_kernel(const float* __restrict__ x,
                                   const float* __restrict__ sums,
                                   const float* __restrict__ sumsq,
                                   const float* __restrict__ gamma,
                                   const float* __restrict__ beta,
                                   float* __restrict__ y, int n4, float inv_n) {
    int i = blockIdx.x * blockDim.x + threadIdx.x;   // float4 index
    if (i < n4) {
        int c0 = (i << 2) & (DFEAT - 1);
        float4 yv = ((const float4*)y)[i];
        float4 xv = ((const float4*)x)[i];
        float o[4] = {yv.x, yv.y, yv.z, yv.w};
        float xi[4] = {xv.x, xv.y, xv.z, xv.w};
        #pragma unroll
        for (int k = 0; k < 4; ++k) {
            int c = c0 + k;
            float mean = sums[c] * inv_n;
            float var = sumsq[c] * inv_n - mean * mean;
            float inv = rsqrtf(var + EPSBN);
            float v = (o[k] - mean) * inv * gamma[c] + beta[c];
            o[k] = xi[k] + fmaxf(v, 0.f);
        }
        ((float4*)y)[i] = make_float4(o[0], o[1], o[2], o[3]);
    }
}

extern "C" void kernel_launch(void* const* d_in, const int* in_sizes, int n_in,
                              void* d_out, int out_size, void* d_ws, size_t ws_size,
                              hipStream_t stream) {
    const float* x     = (const float*)d_in[0];
    const int*   src   = (const int*)d_in[1];
    const int*   dst   = (const int*)d_in[2];
    const float* W     = (const float*)d_in[3];
    const float* bvec  = (const float*)d_in[4];
    const float* gamma = (const float*)d_in[5];
    const float* beta  = (const float*)d_in[6];
    float* out = (float*)d_out;   // y, written once by fused spmm+gemm

    const int n_nodes = in_sizes[0] / DFEAT;
    const int E = in_sizes[1];
    const int NB = (n_nodes + SCB - 1) / SCB;
    const int C = (E + CHUNK - 1) >> CHUNK_LG;          // edge chunks
    const int P = (n_nodes + RNG - 1) / RNG;            // node partitions
    const int N_pad = P * RNG;

    // ws: epack (E int2) | lrank (E u16) | cnt (C*N_pad u16) | deg_out N |
    //     sums 64 | sumsq 64 | deg_in N | row_start N+1 | bsum 64
    char* wsb = (char*)d_ws;
    int2* epack          = (int2*)wsb;
    unsigned short* lrank = (unsigned short*)(wsb + (size_t)E * 8);
    unsigned short* cnt   = lrank + E;
    int*  deg_out_i  = (int*)(cnt + (size_t)C * N_pad);
    float* sums      = (float*)(deg_out_i + n_nodes);
    float* sumsq     = sums + DFEAT;
    int*  deg_in_i   = (int*)(sumsq + DFEAT);
    int*  row_start  = deg_in_i + n_nodes;
    int*  bsum       = row_start + n_nodes + 1;
    // partial aliases the cnt region (dead after fill_kernel):
    // grid_sg*512B = 3.2MB <= C*N_pad*2B = 11.2MB.
    float* partial   = (float*)cnt;

    // zero: deg_out + sums + sumsq (contiguous; bnstat2 atomic-accumulates).
    hipMemsetAsync(deg_out_i, 0, ((size_t)n_nodes + 2 * DFEAT) * sizeof(int), stream);

    hist2d_kernel<<<dim3(C, P), 256, 0, stream>>>(src, dst, lrank, cnt, deg_out_i,
                                                  E, n_nodes, N_pad);

    colscan_kernel<<<(n_nodes + 255) / 256, 256, 0, stream>>>(cnt, deg_in_i,
                                                              n_nodes, N_pad, C);

    scan1_kernel<<<NB, 256, 0, stream>>>(deg_in_i, bsum, n_nodes);
    scan2_kernel<<<1, 64, 0, stream>>>(bsum, row_start, NB, n_nodes);
    scan3_kernel<<<NB, 256, 0, stream>>>(deg_in_i, bsum, row_start, n_nodes);

    fill_kernel<<<(E + 255) / 256, 256, 0, stream>>>(src, dst, lrank, cnt, deg_out_i,
                                                     row_start, epack, E, N_pad);

    int grid_sg = (n_nodes + 15) / 16;
    spmm_gemm_kernel<<<grid_sg, 256, 0, stream>>>(x, row_start, epack,
                                                  W, bvec, out, partial, n_nodes);

    bnstat2_kernel<<<16, 256, 0, stream>>>(partial, sums, grid_sg);

    int n4 = n_nodes * DFEAT / 4;
    bn_relu_res_kernel<<<(n4 + 255) / 256, 256, 0, stream>>>(
        x, sums, sumsq, gamma, beta, out, n4, 1.0f / (float)n_nodes);
}

// Round 7
// 325.472 us; speedup vs baseline: 1.2727x; 1.0127x over previous
//
#include <hip/hip_runtime.h>

#define DFEAT 64
#define EPSBN 1e-5f
#define SCB 2048      // elements per scan block (256 threads x 8)
#define CHUNK_LG 14
#define CHUNK (1 << CHUNK_LG)   // 16384 edges per chunk, C=98
#define RNG2 16384    // nodes per block: byte-packed quad histogram in 32KB
#define HWORDS 8192   // 32KB LDS words; word o&8191, byte o>>13

// ---------------- byte-packed quad histogram + chunk-local rank ----------------
// Round-6 post-mortem: 64KB hist halved work but quartered waves/CU ->
// regression (latency-bound). This version keeps 32KB (5 blocks/CU allowed)
// but packs FOUR u8 counters per word {src_hi,src_lo,dst_hi,dst_lo}: 16384
// nodes covered -> P=7. Per-chunk per-node counts max ~8 (lambda 0.16), so
// u8 never overflows; deg_in<=~45 so even the colscan prefix fits u8.
// Round-5 lesson applied: ZERO global atomics here -- src counts go to a
// cnt_out table and colscan (which already walks all chunks per node) sums
// deg_out. CHUNK 16384: grid 98x7=686 blocks ~2.7/CU -> round-2 occupancy
// at half the edge visits (90MB vs 166MB re-read).
__global__ __launch_bounds__(256) void hist2d_kernel(
        const int* __restrict__ src, const int* __restrict__ dst,
        unsigned char* __restrict__ lrank,
        unsigned char* __restrict__ cnt_in, unsigned char* __restrict__ cnt_out,
        int E, int N, int N_pad) {
    __shared__ int h[HWORDS];
    int tid = threadIdx.x;
    int c = blockIdx.x, p = blockIdx.y;
    int nbeg = p * RNG2;
    for (int i = tid; i < HWORDS; i += 256) h[i] = 0;
    __syncthreads();

    int ebeg = c << CHUNK_LG;
    int eend = min(ebeg + CHUNK, E);
    int nvec = (eend - ebeg) >> 2;              // full int4 groups
    const int4* src4 = (const int4*)(src + ebeg);
    const int4* dst4 = (const int4*)(dst + ebeg);

    int i = tid;
    int4 s4 = make_int4(0, 0, 0, 0), d4 = s4;
    if (i < nvec) { s4 = src4[i]; d4 = dst4[i]; }
    while (i < nvec) {
        int inext = i + 256;
        int4 sn = make_int4(0, 0, 0, 0), dn = sn;
        if (inext < nvec) { sn = src4[inext]; dn = dst4[inext]; }   // prefetch
        int e = ebeg + (i << 2);
        {
            unsigned int o; int sh, ret;
            // src side: bytes 2 (lo half) / 3 (hi half), non-returning
            o = (unsigned int)(s4.x - nbeg);
            if (o < RNG2) atomicAdd(&h[o & (HWORDS - 1)], 0x10000 << ((o >> 13) << 3));
            o = (unsigned int)(s4.y - nbeg);
            if (o < RNG2) atomicAdd(&h[o & (HWORDS - 1)], 0x10000 << ((o >> 13) << 3));
            o = (unsigned int)(s4.z - nbeg);
            if (o < RNG2) atomicAdd(&h[o & (HWORDS - 1)], 0x10000 << ((o >> 13) << 3));
            o = (unsigned int)(s4.w - nbeg);
            if (o < RNG2) atomicAdd(&h[o & (HWORDS - 1)], 0x10000 << ((o >> 13) << 3));
            // dst side: bytes 0/1, returning -> rank byte
            o = (unsigned int)(d4.x - nbeg);
            if (o < RNG2) { sh = (o >> 13) << 3;
                ret = atomicAdd(&h[o & (HWORDS - 1)], 1 << sh);
                lrank[e + 0] = (unsigned char)((unsigned int)ret >> sh); }
            o = (unsigned int)(d4.y - nbeg);
            if (o < RNG2) { sh = (o >> 13) << 3;
                ret = atomicAdd(&h[o & (HWORDS - 1)], 1 << sh);
                lrank[e + 1] = (unsigned char)((unsigned int)ret >> sh); }
            o = (unsigned int)(d4.z - nbeg);
            if (o < RNG2) { sh = (o >> 13) << 3;
                ret = atomicAdd(&h[o & (HWORDS - 1)], 1 << sh);
                lrank[e + 2] = (unsigned char)((unsigned int)ret >> sh); }
            o = (unsigned int)(d4.w - nbeg);
            if (o < RNG2) { sh = (o >> 13) << 3;
                ret = atomicAdd(&h[o & (HWORDS - 1)], 1 << sh);
                lrank[e + 3] = (unsigned char)((unsigned int)ret >> sh); }
        }
        s4 = sn; d4 = dn; i = inext;
    }
    for (int e = ebeg + (nvec << 2) + tid; e < eend; e += 256) {
        unsigned int o = (unsigned int)(src[e] - nbeg);
        if (o < RNG2) atomicAdd(&h[o & (HWORDS - 1)], 0x10000 << ((o >> 13) << 3));
        o = (unsigned int)(dst[e] - nbeg);
        if (o < RNG2) { int sh = (o >> 13) << 3;
            int ret = atomicAdd(&h[o & (HWORDS - 1)], 1 << sh);
            lrank[e] = (unsigned char)((unsigned int)ret >> sh); }
    }
    __syncthreads();

    // flush: word i2 -> node n0 = nbeg+i2 (bytes 0,2), n1 = n0+8192 (bytes 1,3)
    size_t cbase = (size_t)c * N_pad;
    for (int i2 = tid; i2 < HWORDS; i2 += 256) {
        unsigned int v = (unsigned int)h[i2];
        int n0 = nbeg + i2;
        int n1 = n0 + HWORDS;
        if (n0 < N) {
            cnt_in [cbase + n0] = (unsigned char)(v & 0xffu);
            cnt_out[cbase + n0] = (unsigned char)((v >> 16) & 0xffu);
        }
        if (n1 < N) {
            cnt_in [cbase + n1] = (unsigned char)((v >> 8) & 0xffu);
            cnt_out[cbase + n1] = (unsigned char)(v >> 24);
        }
    }
}

// ---------------- column scan: prefix of cnt_in + sum of cnt_out per node ----------------
__global__ void colscan_kernel(unsigned char* __restrict__ cnt_in,
                               const unsigned char* __restrict__ cnt_out,
                               int* __restrict__ deg_in, int* __restrict__ deg_out,
                               int N, int N_pad, int C) {
    int n = blockIdx.x * blockDim.x + threadIdx.x;
    if (n >= N) return;
    int run = 0, dout = 0;
    for (int c = 0; c < C; ++c) {
        size_t idx = (size_t)c * N_pad + n;
        int v = cnt_in[idx];
        cnt_in[idx] = (unsigned char)run;   // exclusive prefix, <= deg_in <= ~45
        run += v;
        dout += cnt_out[idx];
    }
    deg_in[n] = run;
    deg_out[n] = dout;
}

// ---------------- scan pass 1: per-block sums of deg_in ----------------
__global__ void scan1_kernel(const int* __restrict__ deg, int* __restrict__ bsum, int N) {
    __shared__ int red[256];
    int t = threadIdx.x;
    int base = blockIdx.x * SCB + t * 8;
    int s = 0;
    #pragma unroll
    for (int j = 0; j < 8; ++j) { int idx = base + j; if (idx < N) s += deg[idx]; }
    red[t] = s;
    __syncthreads();
    for (int d = 128; d > 0; d >>= 1) { if (t < d) red[t] += red[t + d]; __syncthreads(); }
    if (t == 0) bsum[blockIdx.x] = red[0];
}

// ---------------- scan pass 2: one-wave shuffle exclusive scan (NB <= 64) ----------------
__global__ void scan2_kernel(int* __restrict__ bsum, int* __restrict__ row_start, int NB, int N) {
    int lane = threadIdx.x & 63;
    int v = (lane < NB) ? bsum[lane] : 0;
    int incl = v;
    #pragma unroll
    for (int off = 1; off < 64; off <<= 1) {
        int t = __shfl_up(incl, off);
        if (lane >= off) incl += t;
    }
    if (lane < NB) bsum[lane] = incl - v;
    if (lane == 63) row_start[N] = incl;   // total == E
}

// ---------------- scan pass 3: full exclusive scan -> row_start ----------------
__global__ void scan3_kernel(const int* __restrict__ deg, const int* __restrict__ bsum,
                             int* __restrict__ row_start, int N) {
    __shared__ int sc[256];
    int t = threadIdx.x;
    int base = blockIdx.x * SCB + t * 8;
    int v[8], ex[8];
    int s = 0;
    #pragma unroll
    for (int j = 0; j < 8; ++j) {
        int idx = base + j;
        v[j] = (idx < N) ? deg[idx] : 0;
        ex[j] = s;
        s += v[j];
    }
    sc[t] = s;
    __syncthreads();
    for (int d = 1; d < 256; d <<= 1) {
        int vv = (t >= d) ? sc[t - d] : 0;
        __syncthreads();
        sc[t] += vv;
        __syncthreads();
    }
    int toff = sc[t] - s + bsum[blockIdx.x];
    #pragma unroll
    for (int j = 0; j < 8; ++j) {
        int idx = base + j;
        if (idx < N) row_start[idx] = toff + ex[j];
    }
}

// ---------------- place edges: slot = row_start[d] + pref[c][d] + lrank[e] ----------------
__global__ void fill_kernel(const int* __restrict__ src, const int* __restrict__ dst,
                            const unsigned char* __restrict__ lrank,
                            const unsigned char* __restrict__ cnt_in,
                            const int* __restrict__ deg_out, const int* __restrict__ row_start,
                            int2* __restrict__ epack, int E, int N_pad) {
    int e = blockIdx.x * blockDim.x + threadIdx.x;
    if (e < E) {
        int d = dst[e], s = src[e];
        int c = e >> CHUNK_LG;
        float coef = rsqrtf((float)max(deg_out[s], 1));
        int slot = row_start[d] + (int)cnt_in[(size_t)c * N_pad + d] + (int)lrank[e];
        epack[slot] = make_int2(s, __float_as_int(coef));
    }
}

// ---------------- fused SpMM + GEMM + BN partials: 4 rows per wave ----------------
// Each wave holds 4 full agg rows across its 64 lanes (acc[q] = column lane).
// GEMM tail: y[r][c] = sum_k agg[r][k]*W[k][c] in-wave via v_readlane
// (SGPR broadcast) x Wl[k][lane] from LDS (1 ds_read feeds 4 rows' FMAs).
// BN column partials accumulated in registers (lane == column), one LDS tree
// + 128-float partial store per block (replaces the bnstat1 25.6MB re-read).
__global__ __launch_bounds__(256, 8) void spmm_gemm_kernel(
        const float* __restrict__ x, const int* __restrict__ row_start,
        const int2* __restrict__ epack, const float* __restrict__ W,
        const float* __restrict__ bvec, float* __restrict__ y,
        float* __restrict__ partial, int N) {
    __shared__ float Wl[DFEAT * DFEAT];
    __shared__ float red_s[4][DFEAT];
    __shared__ float red_q[4][DFEAT];
    int tid = threadIdx.x;
    {
        const float4* W4 = (const float4*)W;
        float4* Wl4 = (float4*)Wl;
        #pragma unroll
        for (int j = 0; j < 4; ++j) Wl4[tid + 256 * j] = W4[tid + 256 * j];
    }
    __syncthreads();

    int lane = tid & 63;
    int w = tid >> 6;
    int r0 = blockIdx.x * 16 + w * 4;
    float bv = bvec[lane];

    float acc[4];
    #pragma unroll
    for (int q = 0; q < 4; ++q) {
        float a = 0.f;
        int r = r0 + q;
        if (r < N) {
            int beg = row_start[r];
            int end = row_start[r + 1];
            for (int cb = beg; cb < end; cb += 64) {
                int take = min(64, end - cb);
                int2 p = (lane < take) ? epack[cb + lane] : make_int2(0, 0);
                int j = 0;
                for (; j + 8 <= take; j += 8) {
                    int sj[8]; float cj[8], v[8];
                    #pragma unroll
                    for (int u = 0; u < 8; ++u) {
                        sj[u] = __builtin_amdgcn_readlane(p.x, j + u);
                        cj[u] = __int_as_float(__builtin_amdgcn_readlane(p.y, j + u));
                    }
                    #pragma unroll
                    for (int u = 0; u < 8; ++u) v[u] = x[(size_t)sj[u] * DFEAT + lane];
                    #pragma unroll
                    for (int u = 0; u < 8; ++u) a = fmaf(v[u], cj[u], a);
                }
                for (; j < take; ++j) {
                    int s = __builtin_amdgcn_readlane(p.x, j);
                    float c = __int_as_float(__builtin_amdgcn_readlane(p.y, j));
                    a = fmaf(x[(size_t)s * DFEAT + lane], c, a);
                }
            }
            a *= rsqrtf((float)max(end - beg, 1));   // norm_dst: a = agg[r][lane]
        }
        acc[q] = a;
    }

    // ---- in-wave GEMM tail, W read shared by 4 rows
    float yo0 = 0.f, yo1 = 0.f, yo2 = 0.f, yo3 = 0.f;
    int ai0 = __float_as_int(acc[0]);
    int ai1 = __float_as_int(acc[1]);
    int ai2 = __float_as_int(acc[2]);
    int ai3 = __float_as_int(acc[3]);
    #pragma unroll 8
    for (int k = 0; k < DFEAT; ++k) {
        float wk = Wl[k * DFEAT + lane];     // conflict-free, 1 read / 4 rows
        yo0 = fmaf(__int_as_float(__builtin_amdgcn_readlane(ai0, k)), wk, yo0);
        yo1 = fmaf(__int_as_float(__builtin_amdgcn_readlane(ai1, k)), wk, yo1);
        yo2 = fmaf(__int_as_float(__builtin_amdgcn_readlane(ai2, k)), wk, yo2);
        yo3 = fmaf(__int_as_float(__builtin_amdgcn_readlane(ai3, k)), wk, yo3);
    }

    float yq[4] = {yo0, yo1, yo2, yo3};
    float ps = 0.f, pq = 0.f;                // column (=lane) partial stats
    #pragma unroll
    for (int q = 0; q < 4; ++q) {
        int r = r0 + q;
        if (r < N) {
            float yv = bv + yq[q];
            y[(size_t)r * DFEAT + lane] = yv;
            ps += yv;
            pq = fmaf(yv, yv, pq);
        }
    }

    red_s[w][lane] = ps;
    red_q[w][lane] = pq;
    __syncthreads();
    if (w == 0) {
        float s = red_s[0][lane] + red_s[1][lane] + red_s[2][lane] + red_s[3][lane];
        float q2 = red_q[0][lane] + red_q[1][lane] + red_q[2][lane] + red_q[3][lane];
        float* p = partial + (size_t)blockIdx.x * 128;
        p[lane] = s;
        p[64 + lane] = q2;
    }
}

// ---------------- BN stats finalize: G partials -> sums/sumsq (adjacent) ----------------
// 16 blocks x 32 stripes; 16 atomics per address (trivial serialization).
__global__ void bnstat2_kernel(const float* __restrict__ partial,
                               float* __restrict__ sums, int G) {
    int t = threadIdx.x;
    int j = t & 127, h = t >> 7;
    int stripe = blockIdx.x * 2 + h;         // 0..31
    float s = 0.f;
    for (int g = stripe; g < G; g += 32)
        s += partial[(size_t)g * 128 + j];
    __shared__ float red[2][128];
    red[h][j] = s;
    __syncthreads();
    if (h == 0) atomicAdd(&sums[j], red[0][j] + red[1][j]);   // sums||sumsq contiguous
}

// ---------------- BN (batch stats) + ReLU + residual, float4, in place on y ----------------
__global__ void bn_relu_res_kernel(const float* __restrict__ x,
                                   const float* __restrict__ sums,
                                   const float* __restrict__ sumsq,
                                   const float* __restrict__ gamma,
                                   const float* __restrict__ beta,
                                   float* __restrict__ y, int n4, float inv_n) {
    int i = blockIdx.x * blockDim.x + threadIdx.x;   // float4 index
    if (i < n4) {
        int c0 = (i << 2) & (DFEAT - 1);
        float4 yv = ((const float4*)y)[i];
        float4 xv = ((const float4*)x)[i];
        float o[4] = {yv.x, yv.y, yv.z, yv.w};
        float xi[4] = {xv.x, xv.y, xv.z, xv.w};
        #pragma unroll
        for (int k = 0; k < 4; ++k) {
            int c = c0 + k;
            float mean = sums[c] * inv_n;
            float var = sumsq[c] * inv_n - mean * mean;
            float inv = rsqrtf(var + EPSBN);
            float v = (o[k] - mean) * inv * gamma[c] + beta[c];
            o[k] = xi[k] + fmaxf(v, 0.f);
        }
        ((float4*)y)[i] = make_float4(o[0], o[1], o[2], o[3]);
    }
}

extern "C" void kernel_launch(void* const* d_in, const int* in_sizes, int n_in,
                              void* d_out, int out_size, void* d_ws, size_t ws_size,
                              hipStream_t stream) {
    const float* x     = (const float*)d_in[0];
    const int*   src   = (const int*)d_in[1];
    const int*   dst   = (const int*)d_in[2];
    const float* W     = (const float*)d_in[3];
    const float* bvec  = (const float*)d_in[4];
    const float* gamma = (const float*)d_in[5];
    const float* beta  = (const float*)d_in[6];
    float* out = (float*)d_out;   // y, written once by fused spmm+gemm

    const int n_nodes = in_sizes[0] / DFEAT;
    const int E = in_sizes[1];
    const int NB = (n_nodes + SCB - 1) / SCB;
    const int C = (E + CHUNK - 1) >> CHUNK_LG;          // edge chunks (98)
    const int P = (n_nodes + RNG2 - 1) / RNG2;          // node partitions (7)
    const int N_pad = P * RNG2;                         // 114688
    const size_t tbl = (size_t)C * N_pad;               // 11.2MB per u8 table

    // ws layout:
    //   epack    E int2            (12.8MB)
    //   lrank    E u8 (+pad16)     ( 1.6MB)
    //   cnt_in   C*N_pad u8        (11.2MB)   exclusive-prefix after colscan
    //   cnt_out  C*N_pad u8        (11.2MB)   dead after colscan
    //   deg_out  N int | deg_in N int | sums 64 | sumsq 64 | row_start N+1 | bsum 64
    //   partial aliases cnt_in (dead after fill): grid_sg*512B = 3.2MB <= 11.2MB
    char* wsb = (char*)d_ws;
    int2* epack            = (int2*)wsb;
    unsigned char* lrank   = (unsigned char*)(wsb + (size_t)E * 8);
    size_t lrank_bytes     = ((size_t)E + 15) & ~(size_t)15;
    unsigned char* cnt_in  = lrank + lrank_bytes;
    unsigned char* cnt_out = cnt_in + tbl;
    int*  deg_out_i  = (int*)(cnt_out + tbl);
    int*  deg_in_i   = deg_out_i + n_nodes;
    float* sums      = (float*)(deg_in_i + n_nodes);
    float* sumsq     = sums + DFEAT;
    int*  row_start  = (int*)(sumsq + DFEAT);
    int*  bsum       = row_start + n_nodes + 1;
    float* partial   = (float*)cnt_in;

    // zero: sums+sumsq only (deg_* written by colscan; bnstat2 accumulates)
    hipMemsetAsync(sums, 0, 2 * DFEAT * sizeof(float), stream);

    hist2d_kernel<<<dim3(C, P), 256, 0, stream>>>(src, dst, lrank, cnt_in, cnt_out,
                                                  E, n_nodes, N_pad);

    colscan_kernel<<<(n_nodes + 255) / 256, 256, 0, stream>>>(
        cnt_in, cnt_out, deg_in_i, deg_out_i, n_nodes, N_pad, C);

    scan1_kernel<<<NB, 256, 0, stream>>>(deg_in_i, bsum, n_nodes);
    scan2_kernel<<<1, 64, 0, stream>>>(bsum, row_start, NB, n_nodes);
    scan3_kernel<<<NB, 256, 0, stream>>>(deg_in_i, bsum, row_start, n_nodes);

    fill_kernel<<<(E + 255) / 256, 256, 0, stream>>>(src, dst, lrank, cnt_in,
                                                     deg_out_i, row_start,
                                                     epack, E, N_pad);

    int grid_sg = (n_nodes + 15) / 16;
    spmm_gemm_kernel<<<grid_sg, 256, 0, stream>>>(x, row_start, epack,
                                                  W, bvec, out, partial, n_nodes);

    bnstat2_kernel<<<16, 256, 0, stream>>>(partial, sums, grid_sg);

    int n4 = n_nodes * DFEAT / 4;
    bn_relu_res_kernel<<<(n4 + 255) / 256, 256, 0, stream>>>(
        x, sums, sumsq, gamma, beta, out, n4, 1.0f / (float)n_nodes);
}